// Round 7
// baseline (122.964 us; speedup 1.0000x reference)
//
#include <hip/hip_runtime.h>
#include <hip/hip_bf16.h>

// KAN harmonic-basis GEMM, v7: register-pipelined, barrier-free, LDS-free.
// out[b,h] = sum_{d,f} basis(x[b,d])[f] * W[d,f,h] + sum_d b[d,h]
//
// f=0 + bias -> fp32 partials c_part[8][256], summed in GEMM epilogue.
// f=1..10    -> bf16 MFMA GEMM, M=16384, N=256, K=2560.
// Wave tile 32x64 (it=2, jt=4), block = 4 row-stacked waves (BM=128,BN=64),
// grid 128x4 = 512 blocks = 2 waves/SIMD. Explicit 2-stage pipeline:
//  - A-fragments double-buffered in regs (afa/afb, half-dtile = 5 k-steps);
//    gen chunks for half h+1 interleaved between half h's MFMA steps.
//  - sincos state (s1,c1) persistent per dtile; native __sinf/__cosf;
//    harmonics via product formulas; bf16 pack = bfe+add3+perm (5 instr/pair).
//  - B ping-pong by kt parity, refill-after-use -> every load ~2 k-steps in
//    flight. Wfrag is fragment-linear (FMAP harmonic order) in L2.

#define HOUT 256
#define DDIM 256
#define NKT  80

typedef __bf16 bf16x8 __attribute__((ext_vector_type(8)));
typedef float floatx4 __attribute__((ext_vector_type(4)));

__device__ __forceinline__ unsigned short f2bf(float f) {
    unsigned int u = __float_as_uint(f);
    return (unsigned short)((u + 0x7FFFu + ((u >> 16) & 1u)) >> 16);
}

// pack two fp32 -> bf16x2 (RNE): round both, take high halves via v_perm
__device__ __forceinline__ unsigned int bfpair(float a, float b) {
    unsigned int ua = __float_as_uint(a), ub = __float_as_uint(b);
    ua += 0x7FFFu + ((ua >> 16) & 1u);
    ub += 0x7FFFu + ((ub >> 16) & 1u);
    return __builtin_amdgcn_perm(ub, ua, 0x07060302u);
}

// harmonic value for (half, q) from s1=sin(x), c1=cos(x). Compile-time half/q.
// half0: [s1, c1, s3, c3, s5]   half1: [s2, c2, s4, c4, c5]
__device__ __forceinline__ float hval(int half, int q, float s1, float c1) {
    if (half == 0) {
        if (q == 0) return s1;
        if (q == 1) return c1;
        const float c2 = __builtin_fmaf(c1 + c1, c1, -1.f);
        const float tc = c2 + c2;
        if (q == 2) return __builtin_fmaf(tc, s1, s1);          // sin3
        if (q == 3) return __builtin_fmaf(tc, c1, -c1);         // cos3
        const float s3 = __builtin_fmaf(tc, s1, s1);
        return __builtin_fmaf(tc, s3, -s1);                     // sin5
    } else {
        const float c2 = __builtin_fmaf(c1 + c1, c1, -1.f);
        if (q == 1) return c2;
        if (q == 0) return (s1 + s1) * c1;                      // sin2
        const float tc = c2 + c2;
        if (q == 2) return tc * ((s1 + s1) * c1);               // sin4 = 2c2 s2
        if (q == 3) return __builtin_fmaf(tc, c2, -1.f);        // cos4
        const float c3 = __builtin_fmaf(tc, c1, -c1);
        return __builtin_fmaf(tc, c3, -c1);                     // cos5
    }
}

// Wfrag kt-order within a dtile (FMAP): q0..4 = f{1,2,5,6,9}, q5..9 = f{3,4,7,8,10}
__device__ __constant__ int FMAP[10] = {1, 2, 5, 6, 9, 3, 4, 7, 8, 10};

// grid 88 x 256 threads.
// blocks [0,80): kt; Wfrag[kt][n][dd] = bf16(W[(kt/10)*32+dd][FMAP[kt%10]][n])
// blocks [80,88): p; c_part[p][h] = sum_{d in p*32..+32} W[d][0][h]+b[d][h]
__global__ void prep_kernel(const float* __restrict__ W, const float* __restrict__ bias,
                            unsigned short* __restrict__ Wfrag, float* __restrict__ c_part) {
    const int bid = blockIdx.x;
    const int t = threadIdx.x;
    if (bid < NKT) {
        const int kt = bid;
        const int dtile = kt / 10;
        const int f = FMAP[kt - dtile * 10];
        const float* wsrc = W + ((size_t)(dtile * 32) * 11 + f) * 256 + t;
        union { unsigned short s[32]; int4 v[4]; } buf;
#pragma unroll
        for (int dd = 0; dd < 32; ++dd)
            buf.s[dd] = f2bf(wsrc[(size_t)dd * 11 * 256]);
        int4* dst = (int4*)(Wfrag + ((size_t)kt * 256 + t) * 32);
#pragma unroll
        for (int v = 0; v < 4; ++v) dst[v] = buf.v[v];
    } else {
        const int p = bid - NKT;
        float acc = 0.f;
#pragma unroll
        for (int dd = 0; dd < 32; ++dd) {
            const int d = p * 32 + dd;
            acc += W[(size_t)(d * 11) * 256 + t] + bias[(size_t)d * 256 + t];
        }
        c_part[p * 256 + t] = acc;
    }
}

__device__ __forceinline__ void scchunk(int it, const float4 xq[4],
                                        float s1[2][8], float c1[2][8]) {
    const float4 xa = xq[2 * it], xb = xq[2 * it + 1];
    const float xs[8] = {xa.x, xa.y, xa.z, xa.w, xb.x, xb.y, xb.z, xb.w};
#pragma unroll
    for (int jj = 0; jj < 8; ++jj) {
        s1[it][jj] = __sinf(xs[jj]);
        c1[it][jj] = __cosf(xs[jj]);
    }
}

__device__ __forceinline__ void genchunk(bf16x8 dst[2][5], int half, int q,
                                         const float s1[2][8], const float c1[2][8]) {
#pragma unroll
    for (int it = 0; it < 2; ++it) {
        union { unsigned int u[4]; bf16x8 v; } r;
#pragma unroll
        for (int p = 0; p < 4; ++p)
            r.u[p] = bfpair(hval(half, q, s1[it][2 * p], c1[it][2 * p]),
                            hval(half, q, s1[it][2 * p + 1], c1[it][2 * p + 1]));
        dst[it][q] = r.v;
    }
}

__global__ __launch_bounds__(256, 2)
void kan_gemm(const float* __restrict__ x, const unsigned short* __restrict__ Wfrag,
              const float* __restrict__ c_part, float* __restrict__ out) {
    const int tid = threadIdx.x;
    const int lane = tid & 63;
    const int wave = tid >> 6;
    const int l15 = lane & 15;
    const int koff = lane >> 4;

    const int m0 = blockIdx.x * 128 + wave * 32;
    const int n0 = blockIdx.y * 64;

    const unsigned short* bptr = Wfrag + (size_t)(n0 + l15) * 32 + koff * 8;
    const float* xbase = x + (size_t)(m0 + l15) * DDIM + koff * 8;

    floatx4 acc[2][4];
#pragma unroll
    for (int it = 0; it < 2; ++it)
#pragma unroll
        for (int jt = 0; jt < 4; ++jt)
            acc[it][jt] = (floatx4){0.f, 0.f, 0.f, 0.f};

    // ---- prologue ----
    float4 xq[4];
#pragma unroll
    for (int it = 0; it < 2; ++it) {
        xq[2 * it]     = *(const float4*)(xbase + it * 16 * DDIM);
        xq[2 * it + 1] = *(const float4*)(xbase + it * 16 * DDIM + 4);
    }
    bf16x8 bb[2][4];
#pragma unroll
    for (int jt = 0; jt < 4; ++jt) bb[0][jt] = *(const bf16x8*)(bptr + jt * 512);
#pragma unroll
    for (int jt = 0; jt < 4; ++jt) bb[1][jt] = *(const bf16x8*)(bptr + 8192 + jt * 512);

    float s1[2][8], c1[2][8];
    scchunk(0, xq, s1, c1);
    scchunk(1, xq, s1, c1);

    bf16x8 afa[2][5], afb[2][5];
#pragma unroll
    for (int q = 0; q < 5; ++q) genchunk(afa, 0, q, s1, c1);

    // issue x(t=1)
#pragma unroll
    for (int it = 0; it < 2; ++it) {
        xq[2 * it]     = *(const float4*)(xbase + 32 + it * 16 * DDIM);
        xq[2 * it + 1] = *(const float4*)(xbase + 32 + it * 16 * DDIM + 4);
    }

    // ---- main loop: 8 dtiles, 2 halves each, 5 k-steps per half ----
#pragma unroll 1
    for (int t = 0; t < 8; ++t) {
        const unsigned short* bk = bptr + (size_t)(t * 10) * 8192;

        // half A (kt = 10t+q): MFMA afa; gen afb = half1(t) from state
#pragma unroll
        for (int q = 0; q < 5; ++q) {
#pragma unroll
            for (int it = 0; it < 2; ++it)
#pragma unroll
                for (int jt = 0; jt < 4; ++jt)
                    acc[it][jt] = __builtin_amdgcn_mfma_f32_16x16x32_bf16(
                        afa[it][q], bb[q & 1][jt], acc[it][jt], 0, 0, 0);
            // refill slot with kt+2 (= 10t+q+2, always <= 76)
#pragma unroll
            for (int jt = 0; jt < 4; ++jt)
                bb[q & 1][jt] = *(const bf16x8*)(bk + (size_t)(q + 2) * 8192 + jt * 512);
            genchunk(afb, 1, q, s1, c1);
        }

        // half B (kt = 10t+5+q): MFMA afb; sincos(t+1); x(t+2); gen afa = half0(t+1)
#pragma unroll
        for (int q = 0; q < 5; ++q) {
#pragma unroll
            for (int it = 0; it < 2; ++it)
#pragma unroll
                for (int jt = 0; jt < 4; ++jt)
                    acc[it][jt] = __builtin_amdgcn_mfma_f32_16x16x32_bf16(
                        afb[it][q], bb[(q + 1) & 1][jt], acc[it][jt], 0, 0, 0);
            // refill slot with kt+2 (= 10t+q+7; skip overruns at t=7)
            if (q < 3 || t < 7) {
#pragma unroll
                for (int jt = 0; jt < 4; ++jt)
                    bb[(q + 1) & 1][jt] = *(const bf16x8*)(bk + (size_t)(q + 7) * 8192 + jt * 512);
            }
            if (t < 7) {
                if (q == 0) scchunk(0, xq, s1, c1);
                if (q == 1) {
                    scchunk(1, xq, s1, c1);
                    const int tn = (t + 2 < 8) ? (t + 2) : 7;
                    const float* xn = xbase + tn * 32;
#pragma unroll
                    for (int it = 0; it < 2; ++it) {
                        xq[2 * it]     = *(const float4*)(xn + it * 16 * DDIM);
                        xq[2 * it + 1] = *(const float4*)(xn + it * 16 * DDIM + 4);
                    }
                }
                if (q == 2) { genchunk(afa, 0, 0, s1, c1); genchunk(afa, 0, 1, s1, c1); }
                if (q == 3) { genchunk(afa, 0, 2, s1, c1); genchunk(afa, 0, 3, s1, c1); }
                if (q == 4) { genchunk(afa, 0, 4, s1, c1); }
            }
        }
    }

    // ---- epilogue: C/D layout col = lane&15, row = koff*4 + reg ----
    float cj[4];
#pragma unroll
    for (int jt = 0; jt < 4; ++jt) {
        const int col = n0 + jt * 16 + l15;
        float s = 0.f;
#pragma unroll
        for (int p = 0; p < 8; ++p) s += c_part[p * 256 + col];
        cj[jt] = s;
    }
#pragma unroll
    for (int it = 0; it < 2; ++it) {
        const int row0 = m0 + it * 16 + koff * 4;
#pragma unroll
        for (int jt = 0; jt < 4; ++jt) {
            const int col = n0 + jt * 16 + l15;
#pragma unroll
            for (int r = 0; r < 4; ++r)
                out[(size_t)(row0 + r) * HOUT + col] = acc[it][jt][r] + cj[jt];
        }
    }
}

extern "C" void kernel_launch(void* const* d_in, const int* in_sizes, int n_in,
                              void* d_out, int out_size, void* d_ws, size_t ws_size,
                              hipStream_t stream) {
    const float* x = (const float*)d_in[0];
    const float* W = (const float*)d_in[1];
    const float* b = (const float*)d_in[2];
    float* out = (float*)d_out;

    unsigned short* Wfrag = (unsigned short*)d_ws;                      // 1,310,720 B
    float* c_part = (float*)((char*)d_ws + (size_t)NKT * 256 * 32 * 2); // 8 KB

    prep_kernel<<<NKT + 8, 256, 0, stream>>>(W, b, Wfrag, c_part);
    kan_gemm<<<dim3(128, 4), 256, 0, stream>>>(x, Wfrag, c_part, out);
}

// Round 8
// 121.966 us; speedup vs baseline: 1.0082x; 1.0082x over previous
//
#include <hip/hip_runtime.h>
#include <hip/hip_bf16.h>

// KAN harmonic-basis GEMM, v8: block-wide-N LDS basis (gen-once), K-split-2,
// atomic combine.
// out[b,h] = sum_{d,f} basis(x[b,d])[f] * W[d,f,h] + sum_d b[d,h]
//
// f=0 + bias -> fp32 partials c_part[8][256], added by K-half 0's epilogue.
// f=1..10    -> bf16 MFMA GEMM, M=16384, N=256, K=2560.
// Block: BM=64, BN=256 (4 waves, each 64 rows x 64 cols, it=4, jt=4 -> 16
// MFMA per k-step per wave). Grid 256 x 2 (K split in halves of 4 dtiles);
// halves combine via unsafeAtomicAdd into memset-zeroed out.
// A basis generated ONCE per block (no N-redundancy) into LDS, fragment-
// linear, per-dtile double-buffered (2 x 40 KB = 80 KB -> 2 blocks/CU).
// One barrier per dtile (160 block-MFMAs). B fragments stream from
// L2-resident Wfrag with ping-pong refill-after-use (~2 k-steps in flight).

#define HOUT 256
#define DDIM 256
#define NKT  80

typedef __bf16 bf16x8 __attribute__((ext_vector_type(8)));
typedef float floatx4 __attribute__((ext_vector_type(4)));

__device__ __forceinline__ unsigned short f2bf(float f) {
    unsigned int u = __float_as_uint(f);
    return (unsigned short)((u + 0x7FFFu + ((u >> 16) & 1u)) >> 16);
}

// pack two fp32 -> bf16x2 (RNE), 3 instr: add, add, perm
__device__ __forceinline__ unsigned int bfpair(float a, float b) {
    unsigned int ua = __float_as_uint(a), ub = __float_as_uint(b);
    ua += 0x7FFFu + ((ua >> 16) & 1u);
    ub += 0x7FFFu + ((ub >> 16) & 1u);
    return __builtin_amdgcn_perm(ub, ua, 0x07060302u);
}

// harmonic f = hs+1 from s1=sin(x), c1=cos(x), c2=cos(2x); hs compile-time
__device__ __forceinline__ float harm(int hs, float s1, float c1, float c2) {
    switch (hs) {
    case 0: return s1;
    case 1: return c1;
    case 2: return (s1 + s1) * c1;                                   // sin2
    case 3: return c2;                                               // cos2
    case 4: return __builtin_fmaf(c2 + c2, s1, s1);                  // sin3
    case 5: return __builtin_fmaf(c2 + c2, c1, -c1);                 // cos3
    case 6: return (c2 + c2) * ((s1 + s1) * c1);                     // sin4
    case 7: return __builtin_fmaf(c2 + c2, c2, -1.f);                // cos4
    case 8: { const float s3 = __builtin_fmaf(c2 + c2, s1, s1);
              return __builtin_fmaf(c2 + c2, s3, -s1); }             // sin5
    case 9: { const float c3 = __builtin_fmaf(c2 + c2, c1, -c1);
              return __builtin_fmaf(c2 + c2, c3, -c1); }             // cos5
    }
    return 0.f;
}

// grid 88 x 256 threads.
// blocks [0,80): kt; Wfrag[kt][n][dd] = bf16(W[(kt/10)*32+dd][kt%10+1][n])
// blocks [80,88): p; c_part[p][h] = sum_{d in p*32..+32} W[d][0][h]+b[d][h]
__global__ void prep_kernel(const float* __restrict__ W, const float* __restrict__ bias,
                            unsigned short* __restrict__ Wfrag, float* __restrict__ c_part) {
    const int bid = blockIdx.x;
    const int t = threadIdx.x;
    if (bid < NKT) {
        const int kt = bid;
        const int dtile = kt / 10;
        const int f = kt - dtile * 10 + 1;
        const float* wsrc = W + ((size_t)(dtile * 32) * 11 + f) * 256 + t;
        union { unsigned short s[32]; int4 v[4]; } buf;
#pragma unroll
        for (int dd = 0; dd < 32; ++dd)
            buf.s[dd] = f2bf(wsrc[(size_t)dd * 11 * 256]);
        int4* dst = (int4*)(Wfrag + ((size_t)kt * 256 + t) * 32);
#pragma unroll
        for (int v = 0; v < 4; ++v) dst[v] = buf.v[v];
    } else {
        const int p = bid - NKT;
        float acc = 0.f;
#pragma unroll
        for (int dd = 0; dd < 32; ++dd) {
            const int d = p * 32 + dd;
            acc += W[(size_t)(d * 11) * 256 + t] + bias[(size_t)d * 256 + t];
        }
        c_part[p * 256 + t] = acc;
    }
}

__global__ __launch_bounds__(256, 2)
void kan_gemm(const float* __restrict__ x, const unsigned short* __restrict__ Wfrag,
              const float* __restrict__ c_part, float* __restrict__ out) {
    // A basis, fragment-linear per dtile: tile (hs,itile) at (hs*4+it)*512,
    // lane slot lane*8 (= A[m=l15][k=koff*8+j]). 40 tiles = 40 KB per buffer.
    __shared__ unsigned short As[2][10 * 4 * 512];   // 80 KB

    const int tid = threadIdx.x;
    const int lane = tid & 63;
    const int wave = tid >> 6;
    const int l15 = lane & 15;
    const int koff = lane >> 4;

    const int m0 = blockIdx.x * 64;
    const int khalf = blockIdx.y;
    const int t0 = khalf * 4;        // first dtile of this half
    const int kt0 = khalf * 40;      // first k-tile

    // gen assignment: thread -> row r (64), d-octet o (4)
    const int r = tid & 63;
    const int o = tid >> 6;
    const float* xg = x + (size_t)(m0 + r) * DDIM + o * 8;
    const int gbase = (r >> 4) * 512 + ((r & 15) + 16 * o) * 8;  // + hs*2048

    // B: this wave covers cols n0 = wave*64; frag (kt,jt) = bptr + kt*8192 + jt*512
    const unsigned short* bptr = Wfrag + (size_t)(wave * 64 + l15) * 32 + koff * 8;

    floatx4 acc[4][4];
#pragma unroll
    for (int it = 0; it < 4; ++it)
#pragma unroll
        for (int jt = 0; jt < 4; ++jt)
            acc[it][jt] = (floatx4){0.f, 0.f, 0.f, 0.f};

    // prime B ping-pong (kt0, kt0+1)
    bf16x8 bb[2][4];
#pragma unroll
    for (int jt = 0; jt < 4; ++jt)
        bb[0][jt] = *(const bf16x8*)(bptr + (size_t)kt0 * 8192 + jt * 512);
#pragma unroll
    for (int jt = 0; jt < 4; ++jt)
        bb[1][jt] = *(const bf16x8*)(bptr + (size_t)(kt0 + 1) * 8192 + jt * 512);

    // basis generator for absolute dtile dt into buffer buf
    auto gen = [&](int dt, int buf) {
        const float4 xa = *(const float4*)(xg + dt * 32);
        const float4 xb = *(const float4*)(xg + dt * 32 + 4);
        const float xs[8] = {xa.x, xa.y, xa.z, xa.w, xb.x, xb.y, xb.z, xb.w};
        float s1[8], c1[8], c2[8];
#pragma unroll
        for (int jj = 0; jj < 8; ++jj) {
            s1[jj] = __sinf(xs[jj]);
            c1[jj] = __cosf(xs[jj]);
            c2[jj] = __builtin_fmaf(c1[jj] + c1[jj], c1[jj], -1.f);
        }
        unsigned short* dst = &As[buf][gbase];
#pragma unroll
        for (int hs = 0; hs < 10; ++hs) {
            union { unsigned int u[4]; int4 q; } v;
#pragma unroll
            for (int p = 0; p < 4; ++p)
                v.u[p] = bfpair(harm(hs, s1[2 * p], c1[2 * p], c2[2 * p]),
                                harm(hs, s1[2 * p + 1], c1[2 * p + 1], c2[2 * p + 1]));
            *(int4*)(dst + hs * 2048) = v.q;
        }
    };

    gen(t0, 0);
    __syncthreads();

#pragma unroll 1
    for (int td = 0; td < 4; ++td) {
        // gen next dtile into the other buffer (overlaps this dtile's MFMAs
        // via the co-resident waves; WAR protected by last iter's barrier)
        if (td < 3) gen(t0 + td + 1, (td + 1) & 1);

        const unsigned short* bk = bptr + (size_t)(kt0 + td * 10) * 8192;
        const unsigned short* abuf = As[td & 1];

#pragma unroll
        for (int hs = 0; hs < 10; ++hs) {
            bf16x8 af[4];
#pragma unroll
            for (int it = 0; it < 4; ++it)
                af[it] = *(const bf16x8*)(abuf + (hs * 4 + it) * 512 + lane * 8);
#pragma unroll
            for (int it = 0; it < 4; ++it)
#pragma unroll
                for (int jt = 0; jt < 4; ++jt)
                    acc[it][jt] = __builtin_amdgcn_mfma_f32_16x16x32_bf16(
                        af[it], bb[hs & 1][jt], acc[it][jt], 0, 0, 0);
            // refill used slot with kt+2 (may read a little past Wfrag into
            // d_ws slop on the final steps -- valid memory, values unused)
#pragma unroll
            for (int jt = 0; jt < 4; ++jt)
                bb[hs & 1][jt] = *(const bf16x8*)(bk + (size_t)(hs + 2) * 8192 + jt * 512);
        }
        __syncthreads();
    }

    // epilogue: C/D layout col = lane&15, row = koff*4 + reg.
    // K-half 0 adds the constant term; half 1 adds raw. Combine via atomics.
    float cj[4] = {0.f, 0.f, 0.f, 0.f};
    if (khalf == 0) {
#pragma unroll
        for (int jt = 0; jt < 4; ++jt) {
            const int col = wave * 64 + jt * 16 + l15;
            float s = 0.f;
#pragma unroll
            for (int p = 0; p < 8; ++p) s += c_part[p * 256 + col];
            cj[jt] = s;
        }
    }
#pragma unroll
    for (int it = 0; it < 4; ++it) {
        const int row0 = m0 + it * 16 + koff * 4;
#pragma unroll
        for (int jt = 0; jt < 4; ++jt) {
            const int col = wave * 64 + jt * 16 + l15;
#pragma unroll
            for (int rr = 0; rr < 4; ++rr)
                unsafeAtomicAdd(&out[(size_t)(row0 + rr) * HOUT + col],
                                acc[it][jt][rr] + cj[jt]);
        }
    }
}

extern "C" void kernel_launch(void* const* d_in, const int* in_sizes, int n_in,
                              void* d_out, int out_size, void* d_ws, size_t ws_size,
                              hipStream_t stream) {
    const float* x = (const float*)d_in[0];
    const float* W = (const float*)d_in[1];
    const float* b = (const float*)d_in[2];
    float* out = (float*)d_out;

    unsigned short* Wfrag = (unsigned short*)d_ws;                      // 1,310,720 B
    float* c_part = (float*)((char*)d_ws + (size_t)NKT * 256 * 32 * 2); // 8 KB

    hipMemsetAsync(out, 0, (size_t)out_size * sizeof(float), stream);
    prep_kernel<<<NKT + 8, 256, 0, stream>>>(W, b, Wfrag, c_part);
    kan_gemm<<<dim3(256, 2), 256, 0, stream>>>(x, Wfrag, c_part, out);
}